// Round 6
// baseline (260.247 us; speedup 1.0000x reference)
//
#include <hip/hip_runtime.h>
#include <math.h>

#define TB 2048
#define CC 1024
#define NH 16
#define HD 64

typedef __bf16 bf16x8 __attribute__((ext_vector_type(8)));
typedef __bf16 bf16x4 __attribute__((ext_vector_type(4)));
typedef float  f32x4  __attribute__((ext_vector_type(4)));

__device__ inline float exp2fast(float x) { return __builtin_amdgcn_exp2f(x); }

// async global->LDS, 16B per lane; LDS dest = wave-uniform base + lane*16
__device__ __forceinline__ void gl_lds16(const __bf16* g, __bf16* l) {
    __builtin_amdgcn_global_load_lds(
        (const __attribute__((address_space(1))) void*)g,
        (__attribute__((address_space(3))) void*)l, 16, 0, 0);
}

// ---------------------------------------------------------------------------
// Fused prep: blocks [0,4096) cvt hidden fp32->bf16; [4096,4864) transpose
// W_attn [1024][3072] -> bf16 [3072][1024]; [4864,5120) transpose W_proj.
// ---------------------------------------------------------------------------
__global__ __launch_bounds__(256)
void prep_kernel(const float* __restrict__ hidden, __bf16* __restrict__ hb,
                 const float* __restrict__ Wa, __bf16* __restrict__ wat,
                 const float* __restrict__ Wp, __bf16* __restrict__ wpt)
{
    __shared__ __bf16 L[64][68];
    const int tid = threadIdx.x;
    const int bid = blockIdx.x;
    if (bid < 4096) {
        int i = (bid * 256 + tid) * 4;
        f32x4 v = *(const f32x4*)&hidden[i];
        bf16x4 o;
        o.x = (__bf16)v.x; o.y = (__bf16)v.y; o.z = (__bf16)v.z; o.w = (__bf16)v.w;
        *(bf16x4*)&hb[i] = o;
        return;
    }
    const float* src; __bf16* dst; int N, n0, k0;
    if (bid < 4096 + 768) {
        int t = bid - 4096;
        src = Wa; dst = wat; N = 3072;
        n0 = (t % 48) * 64; k0 = (t / 48) * 64;
    } else {
        int t = bid - 4864;
        src = Wp; dst = wpt; N = 1024;
        n0 = (t % 16) * 64; k0 = (t / 16) * 64;
    }
    #pragma unroll
    for (int i = 0; i < 4; i++) {
        int id = tid + i * 256;
        int r = id >> 4, c = (id & 15) * 4;
        f32x4 v = *(const f32x4*)&src[(size_t)(k0 + r) * N + n0 + c];
        bf16x4 o;
        o.x = (__bf16)v.x; o.y = (__bf16)v.y; o.z = (__bf16)v.z; o.w = (__bf16)v.w;
        *(bf16x4*)&L[r][c] = o;
    }
    __syncthreads();
    #pragma unroll
    for (int i = 0; i < 4; i++) {
        int id = tid + i * 256;
        int nr = id >> 4, kc = (id & 15) * 4;
        bf16x4 o;
        o.x = L[kc + 0][nr]; o.y = L[kc + 1][nr];
        o.z = L[kc + 2][nr]; o.w = L[kc + 3][nr];
        *(bf16x4*)&dst[(size_t)(n0 + nr) * 1024 + k0 + kc] = o;
    }
}

// ---------------------------------------------------------------------------
// bf16 GEMM, B pre-transposed [N][K]. Tile 128 x BN, BK=64. 3-bit XOR
// swizzle on LDS 16B segments -> conflict-free b128 frag reads, coalesced
// staging. acc = C^T (operands swapped) -> vectorized epilogue.
// MODE 0: bias+split+fake-quant -> bf16 q [B,H,T,D] (pre-scaled by
// 0.125*log2e), k [B,H,T,D], v TRANSPOSED [B,H,D,T] (4 scalar stores; 16
// t-consecutive lanes -> 32B chunks) so attention can read V^T fragments
// as contiguous 16B. MODE 1: bias -> fp32 row-major.
// ---------------------------------------------------------------------------
template<int BN, int MODE>
__global__ __launch_bounds__(256)
void gemm_bt(const __bf16* __restrict__ A, const __bf16* __restrict__ Bt,
             const float* __restrict__ bias,
             __bf16* __restrict__ o0, __bf16* __restrict__ o1,
             __bf16* __restrict__ o2, float* __restrict__ of,
             int M, int N, int K,
             const float* __restrict__ scp, const float* __restrict__ zpp)
{
    constexpr int NT = BN / 32;
    __shared__ __bf16 Asm[128][64];
    __shared__ __bf16 Bsm[BN][64];

    const int tid  = threadIdx.x;
    const int m0   = blockIdx.y * 128;
    const int n0   = blockIdx.x * BN;
    const int w    = tid >> 6, lane = tid & 63;
    const int wm   = (w & 1) * 64, wn = (w >> 1) * (BN / 2);
    const int r16  = lane & 15, quad = lane >> 4;
    const int srow = lane >> 3;                    // 0..7 (row within instr)
    const int scol = ((lane & 7) ^ srow) * 8;
    const int rsw  = r16 & 7;

    f32x4 acc[NT][4];
    #pragma unroll
    for (int i = 0; i < NT; i++)
        #pragma unroll
        for (int j = 0; j < 4; j++) acc[i][j] = 0.f;

    for (int k0 = 0; k0 < K; k0 += 64) {
        #pragma unroll
        for (int p = 0; p < 4; p++)
            gl_lds16(&A[(size_t)(m0 + w * 32 + p * 8 + srow) * K + k0 + scol],
                     &Asm[w * 32 + p * 8][0]);
        #pragma unroll
        for (int p = 0; p < BN / 32; p++)
            gl_lds16(&Bt[(size_t)(n0 + w * (BN / 4) + p * 8 + srow) * K + k0 + scol],
                     &Bsm[w * (BN / 4) + p * 8][0]);
        __syncthreads();   // drains vmcnt -> DMA complete

        #pragma unroll
        for (int ks = 0; ks < 2; ks++) {
            const int col = ((ks * 4 + quad) ^ rsw) * 8;
            bf16x8 af[4], bfr[NT];
            #pragma unroll
            for (int mt = 0; mt < 4; mt++)
                af[mt] = *(const bf16x8*)&Asm[wm + mt * 16 + r16][col];
            #pragma unroll
            for (int nt = 0; nt < NT; nt++)
                bfr[nt] = *(const bf16x8*)&Bsm[wn + nt * 16 + r16][col];
            #pragma unroll
            for (int nt = 0; nt < NT; nt++)
                #pragma unroll
                for (int mt = 0; mt < 4; mt++)
                    acc[nt][mt] = __builtin_amdgcn_mfma_f32_16x16x32_bf16(
                        bfr[nt], af[mt], acc[nt][mt], 0, 0, 0);
        }
        __syncthreads();
    }

    const float sc = scp[0];
    const float zp = zpp[0];

    #pragma unroll
    for (int nt = 0; nt < NT; nt++) {
        #pragma unroll
        for (int mt = 0; mt < 4; mt++) {
            int gm = m0 + wm + mt * 16 + r16;           // C row (col of D)
            int gn = n0 + wn + nt * 16 + quad * 4;      // C col base (row of D)
            f32x4 val = acc[nt][mt] + *(const f32x4*)&bias[gn];
            if (MODE == 1) {
                *(f32x4*)&of[(size_t)gm * N + gn] = val;
            } else {
                int part = gn >> 10;
                int idx  = gn & 1023;
                int h = idx >> 6, d = idx & 63;
                int b = gm >> 11, t = gm & 2047;
                if (part == 0) {
                    size_t off = (((size_t)(b * NH + h)) * TB + t) * HD + d;
                    bf16x4 st;
                    #pragma unroll
                    for (int r = 0; r < 4; r++)
                        st[r] = (__bf16)(val[r] * 0.18033688f);  // 0.125*log2e
                    *(bf16x4*)&o0[off] = st;
                } else if (part == 1) {
                    size_t off = (((size_t)(b * NH + h)) * TB + t) * HD + d;
                    bf16x4 st;
                    #pragma unroll
                    for (int r = 0; r < 4; r++) {
                        float qv = val[r] / sc + zp;
                        qv = rintf(qv);                 // half-to-even
                        qv = fminf(fmaxf(qv, 0.f), 255.f);
                        st[r] = (__bf16)((qv - zp) * sc);
                    }
                    *(bf16x4*)&o1[off] = st;
                } else {
                    // V^T store: [b,h,d,t]
                    #pragma unroll
                    for (int r = 0; r < 4; r++) {
                        float qv = val[r] / sc + zp;
                        qv = rintf(qv);                 // half-to-even
                        qv = fminf(fmaxf(qv, 0.f), 255.f);
                        size_t offT = (((size_t)(b * NH + h)) * HD + d + r) * TB + t;
                        o2[offT] = (__bf16)((qv - zp) * sc);
                    }
                }
            }
        }
    }
}

// ---------------------------------------------------------------------------
// Transposed-S MFMA flash attention — NO LDS, NO BARRIERS.
// Round 5: five rounds proved the kernel is lockstep-bound (all pipes <40%,
// every in-phase micro-fix neutral). K/V per (b,h) = 256KB each -> L2
// resident (bid = p*32+bh gives bh%8 -> XCD locality: 4 bh x 512KB = 2MB/L2).
// V^T is produced by gemm1, so every K and V^T MFMA fragment is a contiguous
// 16B global load per lane: LDS staging, transposes, and both barriers are
// deleted. Waves run fully independently -> phase diversity -> VALU/MFMA/
// memory overlap. Causal-pair 512-thread blocks kept ONLY for uniform block
// cost (4 waves on tile 31-p, 4 on tile p: 33 tile-waves/block for every p).
// ---------------------------------------------------------------------------
__global__ __launch_bounds__(512, 4)
void attn_mfma(const __bf16* __restrict__ Q, const __bf16* __restrict__ Kg,
               const __bf16* __restrict__ VgT, __bf16* __restrict__ O)
{
    const int tid  = threadIdx.x;
    const int p    = blockIdx.x >> 5;            // pair index 0..15
    const int bh   = blockIdx.x & 31;            // bh%8 -> XCD
    const int w    = tid >> 6, lane = tid & 63;  // w 0..7
    const int wq   = w & 3;
    const int qt   = (w < 4) ? (31 - p) : p;     // this wave's q-tile
    const int q0   = qt * 64;
    const int l15  = lane & 15, quad = lane >> 4;
    const int b    = bh >> 4, h = bh & 15;

    const __bf16* Kbh = Kg  + (size_t)bh * TB * HD;   // [t][d]
    const __bf16* Vbh = VgT + (size_t)bh * HD * TB;   // [d][t]

    const __bf16* Qrow = Q + ((size_t)bh * TB + q0 + wq * 16 + l15) * HD;
    bf16x8 qf0 = *(const bf16x8*)&Qrow[quad * 8];
    bf16x8 qf1 = *(const bf16x8*)&Qrow[32 + quad * 8];

    const int rbase = (l15 >> 2) * 8 + (l15 & 3);

    bf16x8 af_l;
    {
        __bf16 v = (l15 == 0) ? (__bf16)1.0f : (__bf16)0.0f;
        #pragma unroll
        for (int j = 0; j < 8; j++) af_l[j] = v;
    }

    f32x4 acc_o[4], acc_l;
    #pragma unroll
    for (int nt = 0; nt < 4; nt++) acc_o[nt] = 0.f;
    acc_l = 0.f;
    float mrun = -3.0e38f;

    for (int kt = 0; kt <= qt; kt++) {
        const bool diag = (kt == qt);
        const __bf16* Kt = Kbh + (size_t)kt * 64 * HD;
        const __bf16* Vt = Vbh + (size_t)kt * 64;       // column offset in [d][t]

        f32x4 s[4];
        #pragma unroll
        for (int nt = 0; nt < 4; nt++) s[nt] = 0.f;
        __builtin_amdgcn_s_setprio(1);
        #pragma unroll
        for (int nt = 0; nt < 4; nt++) {
            if (diag && (nt & 1) && wq < 2) continue;   // keys>=32 all masked
            int row = rbase + (nt & 1) * 32 + ((nt >> 1) << 2);
            bf16x8 kf0 = *(const bf16x8*)&Kt[(size_t)row * HD + quad * 8];
            bf16x8 kf1 = *(const bf16x8*)&Kt[(size_t)row * HD + 32 + quad * 8];
            s[nt] = __builtin_amdgcn_mfma_f32_16x16x32_bf16(kf0, qf0, s[nt], 0, 0, 0);
            s[nt] = __builtin_amdgcn_mfma_f32_16x16x32_bf16(kf1, qf1, s[nt], 0, 0, 0);
        }
        __builtin_amdgcn_s_setprio(0);

        // V^T fragment loads issued early: independent of softmax below,
        // ~200cy L2 latency hides under it.
        bf16x8 vf0[4], vf1[4];
        #pragma unroll
        for (int nt = 0; nt < 4; nt++) {
            vf0[nt] = *(const bf16x8*)&Vt[(size_t)(nt * 16 + l15) * TB + quad * 8];
            vf1[nt] = *(const bf16x8*)&Vt[(size_t)(nt * 16 + l15) * TB + 32 + quad * 8];
        }

        if (diag) {
            #pragma unroll
            for (int nt = 0; nt < 4; nt++) {
                int koff = (nt & 1) * 32 + ((nt >> 1) << 2) + quad * 8;
                #pragma unroll
                for (int r = 0; r < 4; r++)
                    if (koff + r > wq * 16 + l15) s[nt][r] = -3.0e38f;
            }
        }

        // balanced max tree (v_max3-friendly)
        float m0 = fmaxf(fmaxf(s[0][0], s[0][1]), fmaxf(s[0][2], s[0][3]));
        float m1 = fmaxf(fmaxf(s[1][0], s[1][1]), fmaxf(s[1][2], s[1][3]));
        float m2 = fmaxf(fmaxf(s[2][0], s[2][1]), fmaxf(s[2][2], s[2][3]));
        float m3 = fmaxf(fmaxf(s[3][0], s[3][1]), fmaxf(s[3][2], s[3][3]));
        float mx = fmaxf(fmaxf(m0, m1), fmaxf(m2, m3));
        mx = fmaxf(mx, __shfl_xor(mx, 16));
        mx = fmaxf(mx, __shfl_xor(mx, 32));

        // T13 defer-max
        if (__any((mx - mrun) > 8.0f)) {
            float mnew  = fmaxf(mrun, mx);
            float alpha = exp2fast(mrun - mnew);
            mrun = mnew;
            #pragma unroll
            for (int nt = 0; nt < 4; nt++)
                #pragma unroll
                for (int r = 0; r < 4; r++) acc_o[nt][r] *= alpha;
            acc_l[0] *= alpha;
        }

        float pv[4][4];
        #pragma unroll
        for (int nt = 0; nt < 4; nt++)
            #pragma unroll
            for (int r = 0; r < 4; r++) pv[nt][r] = exp2fast(s[nt][r] - mrun);

        bf16x8 pf0, pf1;
        #pragma unroll
        for (int j = 0; j < 4; j++) {
            pf0[j]     = (__bf16)pv[0][j];
            pf0[4 + j] = (__bf16)pv[2][j];
            pf1[j]     = (__bf16)pv[1][j];
            pf1[4 + j] = (__bf16)pv[3][j];
        }

        __builtin_amdgcn_s_setprio(1);
        acc_l = __builtin_amdgcn_mfma_f32_16x16x32_bf16(af_l, pf0, acc_l, 0, 0, 0);
        acc_l = __builtin_amdgcn_mfma_f32_16x16x32_bf16(af_l, pf1, acc_l, 0, 0, 0);

        #pragma unroll
        for (int nt = 0; nt < 4; nt++) {
            acc_o[nt] = __builtin_amdgcn_mfma_f32_16x16x32_bf16(vf0[nt], pf0, acc_o[nt], 0, 0, 0);
            acc_o[nt] = __builtin_amdgcn_mfma_f32_16x16x32_bf16(vf1[nt], pf1, acc_o[nt], 0, 0, 0);
        }
        __builtin_amdgcn_s_setprio(0);
    }

    float lall = __shfl(acc_l[0], l15);
    float inv  = 1.f / lall;
    size_t trow = (size_t)(b * TB) + q0 + wq * 16 + l15;
    #pragma unroll
    for (int nt = 0; nt < 4; nt++) {
        bf16x4 st;
        #pragma unroll
        for (int r = 0; r < 4; r++) st[r] = (__bf16)(acc_o[nt][r] * inv);
        *(bf16x4*)&O[trow * CC + h * HD + nt * 16 + quad * 4] = st;
    }
}

extern "C" void kernel_launch(void* const* d_in, const int* in_sizes, int n_in,
                              void* d_out, int out_size, void* d_ws, size_t ws_size,
                              hipStream_t stream) {
    (void)in_sizes; (void)n_in; (void)out_size; (void)ws_size;
    const float* hidden   = (const float*)d_in[0];
    const float* W_attn   = (const float*)d_in[1];
    const float* b_attn   = (const float*)d_in[2];
    const float* W_proj   = (const float*)d_in[3];
    const float* b_proj   = (const float*)d_in[4];
    const float* kv_scale = (const float*)d_in[5];
    const float* kv_zp    = (const float*)d_in[6];
    float* out = (float*)d_out;

    __bf16* hb  = (__bf16*)d_ws;
    __bf16* wat = hb  + (size_t)4096 * 1024;
    __bf16* wpt = wat + (size_t)3072 * 1024;
    __bf16* qws = wpt + (size_t)1024 * 1024;
    __bf16* kws = qws + (size_t)2 * NH * TB * HD;
    __bf16* vws = kws + (size_t)2 * NH * TB * HD;   // V^T [B,H,D,T]
    __bf16* ows = vws + (size_t)2 * NH * TB * HD;

    prep_kernel<<<5120, 256, 0, stream>>>(hidden, hb, W_attn, wat, W_proj, wpt);

    gemm_bt<128, 0><<<dim3(24, 32), 256, 0, stream>>>(
        hb, wat, b_attn, qws, kws, vws, nullptr, 4096, 3072, 1024, kv_scale, kv_zp);

    attn_mfma<<<dim3(16 * 32), 512, 0, stream>>>(qws, kws, vws, ows);

    gemm_bt<64, 1><<<dim3(16, 32), 256, 0, stream>>>(
        ows, wpt, b_proj, nullptr, nullptr, nullptr, out, 4096, 1024, 1024,
        kv_scale, kv_zp);
}

// Round 7
// 185.095 us; speedup vs baseline: 1.4060x; 1.4060x over previous
//
#include <hip/hip_runtime.h>
#include <math.h>

#define TB 2048
#define CC 1024
#define NH 16
#define HD 64

typedef __bf16 bf16x8 __attribute__((ext_vector_type(8)));
typedef __bf16 bf16x4 __attribute__((ext_vector_type(4)));
typedef float  f32x4  __attribute__((ext_vector_type(4)));

__device__ inline float exp2fast(float x) { return __builtin_amdgcn_exp2f(x); }

// async global->LDS, 16B per lane; LDS dest = wave-uniform base + lane*16
__device__ __forceinline__ void gl_lds16(const __bf16* g, __bf16* l) {
    __builtin_amdgcn_global_load_lds(
        (const __attribute__((address_space(1))) void*)g,
        (__attribute__((address_space(3))) void*)l, 16, 0, 0);
}

// ---------------------------------------------------------------------------
// Fused prep: blocks [0,4096) cvt hidden fp32->bf16; [4096,4864) transpose
// W_attn [1024][3072] -> bf16 [3072][1024]; [4864,5120) transpose W_proj.
// ---------------------------------------------------------------------------
__global__ __launch_bounds__(256)
void prep_kernel(const float* __restrict__ hidden, __bf16* __restrict__ hb,
                 const float* __restrict__ Wa, __bf16* __restrict__ wat,
                 const float* __restrict__ Wp, __bf16* __restrict__ wpt)
{
    __shared__ __bf16 L[64][68];
    const int tid = threadIdx.x;
    const int bid = blockIdx.x;
    if (bid < 4096) {
        int i = (bid * 256 + tid) * 4;
        f32x4 v = *(const f32x4*)&hidden[i];
        bf16x4 o;
        o.x = (__bf16)v.x; o.y = (__bf16)v.y; o.z = (__bf16)v.z; o.w = (__bf16)v.w;
        *(bf16x4*)&hb[i] = o;
        return;
    }
    const float* src; __bf16* dst; int N, n0, k0;
    if (bid < 4096 + 768) {
        int t = bid - 4096;
        src = Wa; dst = wat; N = 3072;
        n0 = (t % 48) * 64; k0 = (t / 48) * 64;
    } else {
        int t = bid - 4864;
        src = Wp; dst = wpt; N = 1024;
        n0 = (t % 16) * 64; k0 = (t / 16) * 64;
    }
    #pragma unroll
    for (int i = 0; i < 4; i++) {
        int id = tid + i * 256;
        int r = id >> 4, c = (id & 15) * 4;
        f32x4 v = *(const f32x4*)&src[(size_t)(k0 + r) * N + n0 + c];
        bf16x4 o;
        o.x = (__bf16)v.x; o.y = (__bf16)v.y; o.z = (__bf16)v.z; o.w = (__bf16)v.w;
        *(bf16x4*)&L[r][c] = o;
    }
    __syncthreads();
    #pragma unroll
    for (int i = 0; i < 4; i++) {
        int id = tid + i * 256;
        int nr = id >> 4, kc = (id & 15) * 4;
        bf16x4 o;
        o.x = L[kc + 0][nr]; o.y = L[kc + 1][nr];
        o.z = L[kc + 2][nr]; o.w = L[kc + 3][nr];
        *(bf16x4*)&dst[(size_t)(n0 + nr) * 1024 + k0 + kc] = o;
    }
}

// ---------------------------------------------------------------------------
// QKV GEMM, 256x256 tile, BK=32, 4-slot LDS ring, deep-pipelined (T2+T3+T4+T5).
// M=4096 N=3072 K=1024 fixed. A [M][K] bf16, Bt [N][K] bf16 (K-contig).
// 512 thr = 8 waves (2M x 4N); per-wave output 128x64 = acc[8][4] f32x4.
// LDS: LA/LB[4][256][32] = 128 KiB. Tile t lives in slot t&3; while computing
// tile t we stage tile t+3 (phase A stages its A, phase B its B) -> 3 tiles
// of prefetch in flight; vmcnt(8) once per tile (tail 4/0), NEVER 0 in the
// main loop. Raw s_barrier (no drain) -- cross-wave deps carried by the
// counted vmcnt + barrier chain; no ds_writes exist (DMA only).
// Swizzle: 16B seg s of row r holds global seg s^(r&3); frag read col =
// (quad ^ (r16&3))*8 -> balanced banks (same scheme as proven gemm_bt).
// Bias/scales preloaded + vmcnt(0) BEFORE staging so no stray vmem op can
// pollute the counted vmcnt values.
// Epilogue identical to proven MODE-0: q pre-scaled 0.125*log2e, k/v
// fake-quantized, scattered to [B,H,T,D].
// ---------------------------------------------------------------------------
__global__ __launch_bounds__(512, 2)
void gemm_qkv(const __bf16* __restrict__ A, const __bf16* __restrict__ Bt,
              const float* __restrict__ bias,
              __bf16* __restrict__ o0, __bf16* __restrict__ o1,
              __bf16* __restrict__ o2,
              const float* __restrict__ scp, const float* __restrict__ zpp)
{
    constexpr int K = 1024;
    __shared__ __bf16 LA[4][256][32];
    __shared__ __bf16 LB[4][256][32];

    const int tid  = threadIdx.x;
    const int wg   = blockIdx.x;                 // 0..191
    const int swzb = (wg & 7) * 24 + (wg >> 3);  // XCD-contiguous chunks of 24
    const int m0   = (swzb / 12) * 256;
    const int n0   = (swzb % 12) * 256;

    const int w    = tid >> 6, lane = tid & 63;
    const int wmi  = w >> 2;            // 0..1: 128-row A strip
    const int wni  = w & 3;             // 0..3: 64-row B strip
    const int r16  = lane & 15, quad = lane >> 4;

    // staging: per call 512 lanes cover 128 rows x 32k; wave w rows w*16..+15
    const int srow = lane >> 2;                       // 0..15
    const int scol = ((lane & 3) ^ (srow & 3)) * 8;   // pre-swizzled global seg

    auto stageA = [&](int slot, int t) {
        #pragma unroll
        for (int c = 0; c < 2; c++)
            gl_lds16(&A[(size_t)(m0 + c * 128 + w * 16 + srow) * K + t * 32 + scol],
                     &LA[slot][c * 128 + w * 16][0]);
    };
    auto stageB = [&](int slot, int t) {
        #pragma unroll
        for (int c = 0; c < 2; c++)
            gl_lds16(&Bt[(size_t)(n0 + c * 128 + w * 16 + srow) * K + t * 32 + scol],
                     &LB[slot][c * 128 + w * 16][0]);
    };

    f32x4 acc[8][4];
    #pragma unroll
    for (int i = 0; i < 8; i++)
        #pragma unroll
        for (int j = 0; j < 4; j++) acc[i][j] = 0.f;

    // preload epilogue operands BEFORE staging; drain so vmcnt stays counted
    const float sc = scp[0];
    const float zp = zpp[0];
    f32x4 bias_r[4];
    #pragma unroll
    for (int nt = 0; nt < 4; nt++)
        bias_r[nt] = *(const f32x4*)&bias[n0 + wni * 64 + nt * 16 + quad * 4];
    asm volatile("s_waitcnt vmcnt(0)" ::: "memory");

    // prologue: stage tiles 0,1,2 (12 loads); drain tile 0 (leave 8)
    stageA(0, 0); stageB(0, 0);
    stageA(1, 1); stageB(1, 1);
    stageA(2, 2); stageB(2, 2);
    asm volatile("s_waitcnt vmcnt(8)" ::: "memory");
    __builtin_amdgcn_s_barrier();

    const int colr = (quad ^ (r16 & 3)) * 8;   // read-side inverse swizzle

    for (int t = 0; t < 32; t++) {
        const int slot = t & 3;
        bf16x8 af[4], bfv[4];

        // ---- phase A: B-frags + A mt 0..3, stage A(t+3) ----
        #pragma unroll
        for (int nt = 0; nt < 4; nt++)
            bfv[nt] = *(const bf16x8*)&LB[slot][wni * 64 + nt * 16 + r16][colr];
        #pragma unroll
        for (int m = 0; m < 4; m++)
            af[m] = *(const bf16x8*)&LA[slot][wmi * 128 + m * 16 + r16][colr];
        if (t <= 28) stageA((t + 3) & 3, t + 3);
        __builtin_amdgcn_s_barrier();
        __builtin_amdgcn_s_setprio(1);
        #pragma unroll
        for (int nt = 0; nt < 4; nt++)
            #pragma unroll
            for (int m = 0; m < 4; m++)
                acc[m][nt] = __builtin_amdgcn_mfma_f32_16x16x32_bf16(
                    bfv[nt], af[m], acc[m][nt], 0, 0, 0);
        __builtin_amdgcn_s_setprio(0);
        __builtin_amdgcn_s_barrier();

        // ---- phase B: A mt 4..7, stage B(t+3), counted drain ----
        #pragma unroll
        for (int m = 0; m < 4; m++)
            af[m] = *(const bf16x8*)&LA[slot][wmi * 128 + 64 + m * 16 + r16][colr];
        if (t <= 28) stageB((t + 3) & 3, t + 3);
        // drain so tile t+1 (staged at t-2) is resident after the barrier:
        // outstanding after target = stages of t+2,t+3 = 8 loads (tail: 4/0)
        if (t <= 28)      asm volatile("s_waitcnt vmcnt(8)" ::: "memory");
        else if (t == 29) asm volatile("s_waitcnt vmcnt(4)" ::: "memory");
        else if (t == 30) asm volatile("s_waitcnt vmcnt(0)" ::: "memory");
        __builtin_amdgcn_s_barrier();
        __builtin_amdgcn_s_setprio(1);
        #pragma unroll
        for (int nt = 0; nt < 4; nt++)
            #pragma unroll
            for (int m = 0; m < 4; m++)
                acc[4 + m][nt] = __builtin_amdgcn_mfma_f32_16x16x32_bf16(
                    bfv[nt], af[m], acc[4 + m][nt], 0, 0, 0);
        __builtin_amdgcn_s_setprio(0);
        __builtin_amdgcn_s_barrier();
    }

    // epilogue (proven MODE-0 form)
    #pragma unroll
    for (int nt = 0; nt < 4; nt++) {
        #pragma unroll
        for (int mt = 0; mt < 8; mt++) {
            int gm = m0 + wmi * 128 + mt * 16 + r16;
            int gn = n0 + wni * 64 + nt * 16 + quad * 4;
            f32x4 val = acc[mt][nt] + bias_r[nt];
            int part = gn >> 10;
            int idx  = gn & 1023;
            int h = idx >> 6, d = idx & 63;
            int b = gm >> 11, t = gm & 2047;
            size_t off = (((size_t)(b * NH + h)) * TB + t) * HD + d;
            bf16x4 st;
            if (part == 0) {
                #pragma unroll
                for (int r = 0; r < 4; r++)
                    st[r] = (__bf16)(val[r] * 0.18033688f);  // 0.125*log2e
                *(bf16x4*)&o0[off] = st;
            } else {
                #pragma unroll
                for (int r = 0; r < 4; r++) {
                    float qv = val[r] / sc + zp;
                    qv = rintf(qv);                 // half-to-even
                    qv = fminf(fmaxf(qv, 0.f), 255.f);
                    st[r] = (__bf16)((qv - zp) * sc);
                }
                if (part == 1) *(bf16x4*)&o1[off] = st;
                else           *(bf16x4*)&o2[off] = st;
            }
        }
    }
}

// ---------------------------------------------------------------------------
// bf16 GEMM, B pre-transposed [N][K]. Tile 128 x BN, BK=64. (kept for the
// projection GEMM, MODE 1: bias -> fp32 row-major.)
// ---------------------------------------------------------------------------
template<int BN, int MODE>
__global__ __launch_bounds__(256)
void gemm_bt(const __bf16* __restrict__ A, const __bf16* __restrict__ Bt,
             const float* __restrict__ bias,
             __bf16* __restrict__ o0, __bf16* __restrict__ o1,
             __bf16* __restrict__ o2, float* __restrict__ of,
             int M, int N, int K,
             const float* __restrict__ scp, const float* __restrict__ zpp)
{
    constexpr int NT = BN / 32;
    __shared__ __bf16 Asm[128][64];
    __shared__ __bf16 Bsm[BN][64];

    const int tid  = threadIdx.x;
    const int m0   = blockIdx.y * 128;
    const int n0   = blockIdx.x * BN;
    const int w    = tid >> 6, lane = tid & 63;
    const int wm   = (w & 1) * 64, wn = (w >> 1) * (BN / 2);
    const int r16  = lane & 15, quad = lane >> 4;
    const int srow = lane >> 3;                    // 0..7 (row within instr)
    const int scol = ((lane & 7) ^ srow) * 8;
    const int rsw  = r16 & 7;

    f32x4 acc[NT][4];
    #pragma unroll
    for (int i = 0; i < NT; i++)
        #pragma unroll
        for (int j = 0; j < 4; j++) acc[i][j] = 0.f;

    for (int k0 = 0; k0 < K; k0 += 64) {
        #pragma unroll
        for (int p = 0; p < 4; p++)
            gl_lds16(&A[(size_t)(m0 + w * 32 + p * 8 + srow) * K + k0 + scol],
                     &Asm[w * 32 + p * 8][0]);
        #pragma unroll
        for (int p = 0; p < BN / 32; p++)
            gl_lds16(&Bt[(size_t)(n0 + w * (BN / 4) + p * 8 + srow) * K + k0 + scol],
                     &Bsm[w * (BN / 4) + p * 8][0]);
        __syncthreads();   // drains vmcnt -> DMA complete

        #pragma unroll
        for (int ks = 0; ks < 2; ks++) {
            const int col = ((ks * 4 + quad) ^ rsw) * 8;
            bf16x8 af[4], bfr[NT];
            #pragma unroll
            for (int mt = 0; mt < 4; mt++)
                af[mt] = *(const bf16x8*)&Asm[wm + mt * 16 + r16][col];
            #pragma unroll
            for (int nt = 0; nt < NT; nt++)
                bfr[nt] = *(const bf16x8*)&Bsm[wn + nt * 16 + r16][col];
            #pragma unroll
            for (int nt = 0; nt < NT; nt++)
                #pragma unroll
                for (int mt = 0; mt < 4; mt++)
                    acc[nt][mt] = __builtin_amdgcn_mfma_f32_16x16x32_bf16(
                        bfr[nt], af[mt], acc[nt][mt], 0, 0, 0);
        }
        __syncthreads();
    }

    const float sc = scp[0];
    const float zp = zpp[0];

    #pragma unroll
    for (int nt = 0; nt < NT; nt++) {
        #pragma unroll
        for (int mt = 0; mt < 4; mt++) {
            int gm = m0 + wm + mt * 16 + r16;           // C row (col of D)
            int gn = n0 + wn + nt * 16 + quad * 4;      // C col base (row of D)
            f32x4 val = acc[nt][mt] + *(const f32x4*)&bias[gn];
            if (MODE == 1) {
                *(f32x4*)&of[(size_t)gm * N + gn] = val;
            } else {
                int part = gn >> 10;
                int idx  = gn & 1023;
                int h = idx >> 6, d = idx & 63;
                int b = gm >> 11, t = gm & 2047;
                size_t off = (((size_t)(b * NH + h)) * TB + t) * HD + d;
                bf16x4 st;
                if (part == 0) {
                    #pragma unroll
                    for (int r = 0; r < 4; r++)
                        st[r] = (__bf16)(val[r] * 0.18033688f);  // 0.125*log2e
                    *(bf16x4*)&o0[off] = st;
                } else {
                    #pragma unroll
                    for (int r = 0; r < 4; r++) {
                        float qv = val[r] / sc + zp;
                        qv = rintf(qv);                 // half-to-even
                        qv = fminf(fmaxf(qv, 0.f), 255.f);
                        st[r] = (__bf16)((qv - zp) * sc);
                    }
                    if (part == 1) *(bf16x4*)&o1[off] = st;
                    else           *(bf16x4*)&o2[off] = st;
                }
            }
        }
    }
}

// ---------------------------------------------------------------------------
// Transposed-S MFMA flash attention — causal-pair blocks (round-3 proven
// 41.8us config, reverted after round-4/5 experiments regressed).
// ---------------------------------------------------------------------------
__global__ __launch_bounds__(512, 4)
void attn_mfma(const __bf16* __restrict__ Q, const __bf16* __restrict__ Kg,
               const __bf16* __restrict__ Vg, __bf16* __restrict__ O)
{
    __shared__ alignas(16) __bf16 Ksm[64][72];   // [key][d]
    __shared__ alignas(16) __bf16 Vsm[64][72];   // [d][key]

    const int tid  = threadIdx.x;
    const int p    = blockIdx.x >> 5;            // pair index 0..15, heavy first
    const int bh   = blockIdx.x & 31;
    const int w    = tid >> 6, lane = tid & 63;  // w 0..7
    const int wq   = w & 3;
    const int qt   = (w < 4) ? (31 - p) : p;     // this wave's q-tile
    const int ktmax = 31 - p;                    // union of both tiles' extents
    const int q0   = qt * 64;
    const int l15  = lane & 15, quad = lane >> 4;
    const int b    = bh >> 4, h = bh & 15;

    const int krow = tid >> 3;            // 0..63 (512 threads stage all rows)
    const int kseg = (tid & 7) * 8;
    const int vkey = tid & 63;
    const int vc   = tid >> 6;            // 0..7

    const __bf16* Kbh = Kg + (size_t)bh * TB * HD;
    const __bf16* Vbh = Vg + (size_t)bh * TB * HD;

    const __bf16* Qrow = Q + ((size_t)bh * TB + q0 + wq * 16 + l15) * HD;
    bf16x8 qf0 = *(const bf16x8*)&Qrow[quad * 8];
    bf16x8 qf1 = *(const bf16x8*)&Qrow[32 + quad * 8];

    const int rbase = (l15 >> 2) * 8 + (l15 & 3);

    bf16x8 af_l;
    {
        __bf16 v = (l15 == 0) ? (__bf16)1.0f : (__bf16)0.0f;
        #pragma unroll
        for (int j = 0; j < 8; j++) af_l[j] = v;
    }

    f32x4 acc_o[4], acc_l;
    #pragma unroll
    for (int nt = 0; nt < 4; nt++) acc_o[nt] = 0.f;
    acc_l = 0.f;
    float mrun = -3.0e38f;

    bf16x8 kpre = *(const bf16x8*)&Kbh[(size_t)krow * HD + kseg];
    bf16x8 vpre = *(const bf16x8*)&Vbh[(size_t)vkey * HD + vc * 8];

    for (int kt = 0; kt <= ktmax; kt++) {
        __syncthreads();
        *(bf16x8*)&Ksm[krow][kseg] = kpre;
        #pragma unroll
        for (int j = 0; j < 8; j++)
            Vsm[vc * 8 + j][vkey] = vpre[j];
        __syncthreads();

        if (kt < ktmax) {
            const __bf16* Kn = Kbh + (size_t)(kt + 1) * 64 * HD;
            const __bf16* Vn = Vbh + (size_t)(kt + 1) * 64 * HD;
            kpre = *(const bf16x8*)&Kn[(size_t)krow * HD + kseg];
            vpre = *(const bf16x8*)&Vn[(size_t)vkey * HD + vc * 8];
        }

        if (kt > qt) continue;           // this wave's tile done; keep syncing

        const bool diag = (kt == qt);

        f32x4 s[4];
        #pragma unroll
        for (int nt = 0; nt < 4; nt++) s[nt] = 0.f;
        __builtin_amdgcn_s_setprio(1);
        #pragma unroll
        for (int nt = 0; nt < 4; nt++) {
            if (diag && (nt & 1) && wq < 2) continue;   // keys>=32 all masked
            int row = rbase + (nt & 1) * 32 + ((nt >> 1) << 2);
            bf16x8 kf0 = *(const bf16x8*)&Ksm[row][quad * 8];
            bf16x8 kf1 = *(const bf16x8*)&Ksm[row][32 + quad * 8];
            s[nt] = __builtin_amdgcn_mfma_f32_16x16x32_bf16(kf0, qf0, s[nt], 0, 0, 0);
            s[nt] = __builtin_amdgcn_mfma_f32_16x16x32_bf16(kf1, qf1, s[nt], 0, 0, 0);
        }
        __builtin_amdgcn_s_setprio(0);

        if (diag) {
            #pragma unroll
            for (int nt = 0; nt < 4; nt++) {
                int koff = (nt & 1) * 32 + ((nt >> 1) << 2) + quad * 8;
                #pragma unroll
                for (int r = 0; r < 4; r++)
                    if (koff + r > wq * 16 + l15) s[nt][r] = -3.0e38f;
            }
        }

        // balanced max tree (v_max3-friendly)
        float m0 = fmaxf(fmaxf(s[0][0], s[0][1]), fmaxf(s[0][2], s[0][3]));
        float m1 = fmaxf(fmaxf(s[1][0], s[1][1]), fmaxf(s[1][2], s[1][3]));
        float m2 = fmaxf(fmaxf(s[2][0], s[2][1]), fmaxf(s[2][2], s[2][3]));
        float m3 = fmaxf(fmaxf(s[3][0], s[3][1]), fmaxf(s[3][2], s[3][3]));
        float mx = fmaxf(fmaxf(m0, m1), fmaxf(m2, m3));
        mx = fmaxf(mx, __shfl_xor(mx, 16));
        mx = fmaxf(mx, __shfl_xor(mx, 32));

        // T13 defer-max
        if (__any((mx - mrun) > 8.0f)) {
            float mnew  = fmaxf(mrun, mx);
            float alpha = exp2fast(mrun - mnew);
            mrun = mnew;
            #pragma unroll
            for (int nt = 0; nt < 4; nt++)
                #pragma unroll
                for (int r = 0; r < 4; r++) acc_o[nt][r] *= alpha;
            acc_l[0] *= alpha;
        }

        float pv[4][4];
        #pragma unroll
        for (int nt = 0; nt < 4; nt++)
            #pragma unroll
            for (int r = 0; r < 4; r++) pv[nt][r] = exp2fast(s[nt][r] - mrun);

        bf16x8 pf0, pf1;
        #pragma unroll
        for (int j = 0; j < 4; j++) {
            pf0[j]     = (__bf16)pv[0][j];
            pf0[4 + j] = (__bf16)pv[2][j];
            pf1[j]     = (__bf16)pv[1][j];
            pf1[4 + j] = (__bf16)pv[3][j];
        }

        __builtin_amdgcn_s_setprio(1);
        acc_l = __builtin_amdgcn_mfma_f32_16x16x32_bf16(af_l, pf0, acc_l, 0, 0, 0);
        acc_l = __builtin_amdgcn_mfma_f32_16x16x32_bf16(af_l, pf1, acc_l, 0, 0, 0);

        #pragma unroll
        for (int nt = 0; nt < 4; nt++) {
            bf16x8 vf0 = *(const bf16x8*)&Vsm[nt * 16 + l15][quad * 8];
            bf16x8 vf1 = *(const bf16x8*)&Vsm[nt * 16 + l15][32 + quad * 8];
            acc_o[nt] = __builtin_amdgcn_mfma_f32_16x16x32_bf16(vf0, pf0, acc_o[nt], 0, 0, 0);
            acc_o[nt] = __builtin_amdgcn_mfma_f32_16x16x32_bf16(vf1, pf1, acc_o[nt], 0, 0, 0);
        }
        __builtin_amdgcn_s_setprio(0);
    }

    float lall = __shfl(acc_l[0], l15);
    float inv  = 1.f / lall;
    size_t trow = (size_t)(b * TB) + q0 + wq * 16 + l15;
    #pragma unroll
    for (int nt = 0; nt < 4; nt++) {
        bf16x4 st;
        #pragma unroll
        for (int r = 0; r < 4; r++) st[r] = (__bf16)(acc_o[nt][r] * inv);
        *(bf16x4*)&O[trow * CC + h * HD + nt * 16 + quad * 4] = st;
    }
}

extern "C" void kernel_launch(void* const* d_in, const int* in_sizes, int n_in,
                              void* d_out, int out_size, void* d_ws, size_t ws_size,
                              hipStream_t stream) {
    (void)in_sizes; (void)n_in; (void)out_size; (void)ws_size;
    const float* hidden   = (const float*)d_in[0];
    const float* W_attn   = (const float*)d_in[1];
    const float* b_attn   = (const float*)d_in[2];
    const float* W_proj   = (const float*)d_in[3];
    const float* b_proj   = (const float*)d_in[4];
    const float* kv_scale = (const float*)d_in[5];
    const float* kv_zp    = (const float*)d_in[6];
    float* out = (float*)d_out;

    __bf16* hb  = (__bf16*)d_ws;
    __bf16* wat = hb  + (size_t)4096 * 1024;
    __bf16* wpt = wat + (size_t)3072 * 1024;
    __bf16* qws = wpt + (size_t)1024 * 1024;
    __bf16* kws = qws + (size_t)2 * NH * TB * HD;
    __bf16* vws = kws + (size_t)2 * NH * TB * HD;
    __bf16* ows = vws + (size_t)2 * NH * TB * HD;

    prep_kernel<<<5120, 256, 0, stream>>>(hidden, hb, W_attn, wat, W_proj, wpt);

    gemm_qkv<<<192, 512, 0, stream>>>(
        hb, wat, b_attn, qws, kws, vws, kv_scale, kv_zp);

    attn_mfma<<<dim3(16 * 32), 512, 0, stream>>>(qws, kws, vws, ows);

    gemm_bt<64, 1><<<dim3(16, 32), 256, 0, stream>>>(
        ows, wpt, b_proj, nullptr, nullptr, nullptr, out, 4096, 1024, 1024,
        kv_scale, kv_zp);
}

// Round 8
// 184.175 us; speedup vs baseline: 1.4130x; 1.0050x over previous
//
#include <hip/hip_runtime.h>
#include <math.h>

#define TB 2048
#define CC 1024
#define NH 16
#define HD 64

typedef __bf16 bf16x8 __attribute__((ext_vector_type(8)));
typedef __bf16 bf16x4 __attribute__((ext_vector_type(4)));
typedef float  f32x4  __attribute__((ext_vector_type(4)));

__device__ inline float exp2fast(float x) { return __builtin_amdgcn_exp2f(x); }

// async global->LDS, 16B per lane; LDS dest = wave-uniform base + lane*16
__device__ __forceinline__ void gl_lds16(const __bf16* g, __bf16* l) {
    __builtin_amdgcn_global_load_lds(
        (const __attribute__((address_space(1))) void*)g,
        (__attribute__((address_space(3))) void*)l, 16, 0, 0);
}

// ---------------------------------------------------------------------------
// Fused prep: blocks [0,4096) cvt hidden fp32->bf16; [4096,4864) transpose
// W_attn [1024][3072] -> bf16 [3072][1024]; [4864,5120) transpose W_proj.
// ---------------------------------------------------------------------------
__global__ __launch_bounds__(256)
void prep_kernel(const float* __restrict__ hidden, __bf16* __restrict__ hb,
                 const float* __restrict__ Wa, __bf16* __restrict__ wat,
                 const float* __restrict__ Wp, __bf16* __restrict__ wpt)
{
    __shared__ __bf16 L[64][68];
    const int tid = threadIdx.x;
    const int bid = blockIdx.x;
    if (bid < 4096) {
        int i = (bid * 256 + tid) * 4;
        f32x4 v = *(const f32x4*)&hidden[i];
        bf16x4 o;
        o.x = (__bf16)v.x; o.y = (__bf16)v.y; o.z = (__bf16)v.z; o.w = (__bf16)v.w;
        *(bf16x4*)&hb[i] = o;
        return;
    }
    const float* src; __bf16* dst; int N, n0, k0;
    if (bid < 4096 + 768) {
        int t = bid - 4096;
        src = Wa; dst = wat; N = 3072;
        n0 = (t % 48) * 64; k0 = (t / 48) * 64;
    } else {
        int t = bid - 4864;
        src = Wp; dst = wpt; N = 1024;
        n0 = (t % 16) * 64; k0 = (t / 16) * 64;
    }
    #pragma unroll
    for (int i = 0; i < 4; i++) {
        int id = tid + i * 256;
        int r = id >> 4, c = (id & 15) * 4;
        f32x4 v = *(const f32x4*)&src[(size_t)(k0 + r) * N + n0 + c];
        bf16x4 o;
        o.x = (__bf16)v.x; o.y = (__bf16)v.y; o.z = (__bf16)v.z; o.w = (__bf16)v.w;
        *(bf16x4*)&L[r][c] = o;
    }
    __syncthreads();
    #pragma unroll
    for (int i = 0; i < 4; i++) {
        int id = tid + i * 256;
        int nr = id >> 4, kc = (id & 15) * 4;
        bf16x4 o;
        o.x = L[kc + 0][nr]; o.y = L[kc + 1][nr];
        o.z = L[kc + 2][nr]; o.w = L[kc + 3][nr];
        *(bf16x4*)&dst[(size_t)(n0 + nr) * 1024 + k0 + kc] = o;
    }
}

// ---------------------------------------------------------------------------
// bf16 GEMM, B pre-transposed [N][K]. Tile 128 x BN, BK=64. 3-bit XOR
// swizzle on LDS 16B segments -> conflict-free b128 frag reads, coalesced
// staging. acc = C^T (operands swapped) -> vectorized epilogue.
// (Round 7: gemm_qkv 256^2 pipeline reverted -- 48.5us vs this structure's
// ~30us; 192 blocks left 25% of CUs idle and 1 block/CU lost the implicit
// 3-block/CU overlap that makes this m97-style loop work.)
// MODE 0: bias+split+fake-quant -> bf16 q/k/v [B,H,T,D]; Q pre-scaled by
// 0.125*log2(e). MODE 1: bias -> fp32 row-major.
// ---------------------------------------------------------------------------
template<int BN, int MODE>
__global__ __launch_bounds__(256)
void gemm_bt(const __bf16* __restrict__ A, const __bf16* __restrict__ Bt,
             const float* __restrict__ bias,
             __bf16* __restrict__ o0, __bf16* __restrict__ o1,
             __bf16* __restrict__ o2, float* __restrict__ of,
             int M, int N, int K,
             const float* __restrict__ scp, const float* __restrict__ zpp)
{
    constexpr int NT = BN / 32;
    __shared__ __bf16 Asm[128][64];
    __shared__ __bf16 Bsm[BN][64];

    const int tid  = threadIdx.x;
    const int m0   = blockIdx.y * 128;
    const int n0   = blockIdx.x * BN;
    const int w    = tid >> 6, lane = tid & 63;
    const int wm   = (w & 1) * 64, wn = (w >> 1) * (BN / 2);
    const int r16  = lane & 15, quad = lane >> 4;
    const int srow = lane >> 3;                    // 0..7 (row within instr)
    const int scol = ((lane & 7) ^ srow) * 8;
    const int rsw  = r16 & 7;

    f32x4 acc[NT][4];
    #pragma unroll
    for (int i = 0; i < NT; i++)
        #pragma unroll
        for (int j = 0; j < 4; j++) acc[i][j] = 0.f;

    for (int k0 = 0; k0 < K; k0 += 64) {
        #pragma unroll
        for (int p = 0; p < 4; p++)
            gl_lds16(&A[(size_t)(m0 + w * 32 + p * 8 + srow) * K + k0 + scol],
                     &Asm[w * 32 + p * 8][0]);
        #pragma unroll
        for (int p = 0; p < BN / 32; p++)
            gl_lds16(&Bt[(size_t)(n0 + w * (BN / 4) + p * 8 + srow) * K + k0 + scol],
                     &Bsm[w * (BN / 4) + p * 8][0]);
        __syncthreads();   // drains vmcnt -> DMA complete

        #pragma unroll
        for (int ks = 0; ks < 2; ks++) {
            const int col = ((ks * 4 + quad) ^ rsw) * 8;
            bf16x8 af[4], bfr[NT];
            #pragma unroll
            for (int mt = 0; mt < 4; mt++)
                af[mt] = *(const bf16x8*)&Asm[wm + mt * 16 + r16][col];
            #pragma unroll
            for (int nt = 0; nt < NT; nt++)
                bfr[nt] = *(const bf16x8*)&Bsm[wn + nt * 16 + r16][col];
            #pragma unroll
            for (int nt = 0; nt < NT; nt++)
                #pragma unroll
                for (int mt = 0; mt < 4; mt++)
                    acc[nt][mt] = __builtin_amdgcn_mfma_f32_16x16x32_bf16(
                        bfr[nt], af[mt], acc[nt][mt], 0, 0, 0);
        }
        __syncthreads();
    }

    const float sc = scp[0];
    const float zp = zpp[0];

    #pragma unroll
    for (int nt = 0; nt < NT; nt++) {
        #pragma unroll
        for (int mt = 0; mt < 4; mt++) {
            int gm = m0 + wm + mt * 16 + r16;           // C row (col of D)
            int gn = n0 + wn + nt * 16 + quad * 4;      // C col base (row of D)
            f32x4 val = acc[nt][mt] + *(const f32x4*)&bias[gn];
            if (MODE == 1) {
                *(f32x4*)&of[(size_t)gm * N + gn] = val;
            } else {
                int part = gn >> 10;
                int idx  = gn & 1023;
                int h = idx >> 6, d = idx & 63;
                int b = gm >> 11, t = gm & 2047;
                size_t off = (((size_t)(b * NH + h)) * TB + t) * HD + d;
                bf16x4 st;
                if (part == 0) {
                    #pragma unroll
                    for (int r = 0; r < 4; r++)
                        st[r] = (__bf16)(val[r] * 0.18033688f);  // 0.125*log2e
                    *(bf16x4*)&o0[off] = st;
                } else {
                    #pragma unroll
                    for (int r = 0; r < 4; r++) {
                        float qv = val[r] / sc + zp;
                        qv = rintf(qv);                 // half-to-even
                        qv = fminf(fmaxf(qv, 0.f), 255.f);
                        st[r] = (__bf16)((qv - zp) * sc);
                    }
                    if (part == 1) *(bf16x4*)&o1[off] = st;
                    else           *(bf16x4*)&o2[off] = st;
                }
            }
        }
    }
}

// ---------------------------------------------------------------------------
// Transposed-S MFMA flash attention — 128-ROW Q-TILE blocks.
// Round 7 restructure: the causal-pair scheme idled ~30% of wave-cycles
// (light-tile waves continue-sync for 31-2p iterations). Now each 512-thread
// block owns ONE 128-row q-tile: wave w (0..7) owns q rows qt128*128+w*16
// ..+15; block loops kt = 0..2*qt128+1. Wave w's diagonal kt is
// kdiag = 2*qt128 + (w>>2), and its rel-row base inside that 64-key tile is
// 16*(w&3) -- identical geometry to the old wq, so the proven inner body
// (masks, softmax, MFMA layout) is carried over verbatim. Wave idling drops
// to ~5% (half the waves idle only on the final kt); block loop-steps
// (staging+barriers) drop ~30% (49 -> 34 per CU). Grid 16 qtiles x 32 bh =
// 512 blocks, heavy-first so the scheduler pairs heavy+light per CU.
// Kept: T13 defer-max, setprio, balanced max tree, padded [64][72] LDS.
// ---------------------------------------------------------------------------
__global__ __launch_bounds__(512, 4)
void attn_mfma(const __bf16* __restrict__ Q, const __bf16* __restrict__ Kg,
               const __bf16* __restrict__ Vg, __bf16* __restrict__ O)
{
    __shared__ alignas(16) __bf16 Ksm[64][72];   // [key][d]
    __shared__ alignas(16) __bf16 Vsm[64][72];   // [d][key]

    const int tid   = threadIdx.x;
    const int qt128 = 15 - (blockIdx.x >> 5);    // heavy q-tiles first
    const int bh    = blockIdx.x & 31;
    const int w     = tid >> 6, lane = tid & 63; // w 0..7
    const int wq    = w & 3;                     // rel 16-row group in diag tile
    const int kdiag = 2 * qt128 + (w >> 2);      // this wave's diagonal kt
    const int ktmax = 2 * qt128 + 1;             // block loop bound
    const int l15   = lane & 15, quad = lane >> 4;
    const int b     = bh >> 4, h = bh & 15;

    const int krow = tid >> 3;            // 0..63 (512 threads stage all rows)
    const int kseg = (tid & 7) * 8;
    const int vkey = tid & 63;
    const int vc   = tid >> 6;            // 0..7

    const __bf16* Kbh = Kg + (size_t)bh * TB * HD;
    const __bf16* Vbh = Vg + (size_t)bh * TB * HD;

    const int qrow = qt128 * 128 + w * 16;       // wave's global q-row base
    const __bf16* Qrow = Q + ((size_t)bh * TB + qrow + l15) * HD;
    bf16x8 qf0 = *(const bf16x8*)&Qrow[quad * 8];
    bf16x8 qf1 = *(const bf16x8*)&Qrow[32 + quad * 8];

    const int rbase = (l15 >> 2) * 8 + (l15 & 3);

    bf16x8 af_l;
    {
        __bf16 v = (l15 == 0) ? (__bf16)1.0f : (__bf16)0.0f;
        #pragma unroll
        for (int j = 0; j < 8; j++) af_l[j] = v;
    }

    f32x4 acc_o[4], acc_l;
    #pragma unroll
    for (int nt = 0; nt < 4; nt++) acc_o[nt] = 0.f;
    acc_l = 0.f;
    float mrun = -3.0e38f;

    bf16x8 kpre = *(const bf16x8*)&Kbh[(size_t)krow * HD + kseg];
    bf16x8 vpre = *(const bf16x8*)&Vbh[(size_t)vkey * HD + vc * 8];

    for (int kt = 0; kt <= ktmax; kt++) {
        __syncthreads();
        *(bf16x8*)&Ksm[krow][kseg] = kpre;
        #pragma unroll
        for (int j = 0; j < 8; j++)
            Vsm[vc * 8 + j][vkey] = vpre[j];
        __syncthreads();

        if (kt < ktmax) {
            const __bf16* Kn = Kbh + (size_t)(kt + 1) * 64 * HD;
            const __bf16* Vn = Vbh + (size_t)(kt + 1) * 64 * HD;
            kpre = *(const bf16x8*)&Kn[(size_t)krow * HD + kseg];
            vpre = *(const bf16x8*)&Vn[(size_t)vkey * HD + vc * 8];
        }

        if (kt > kdiag) continue;        // only half the waves, only last kt

        const bool diag = (kt == kdiag);

        f32x4 s[4];
        #pragma unroll
        for (int nt = 0; nt < 4; nt++) s[nt] = 0.f;
        __builtin_amdgcn_s_setprio(1);
        #pragma unroll
        for (int nt = 0; nt < 4; nt++) {
            if (diag && (nt & 1) && wq < 2) continue;   // keys>=32 all masked
            int row = rbase + (nt & 1) * 32 + ((nt >> 1) << 2);
            bf16x8 kf0 = *(const bf16x8*)&Ksm[row][quad * 8];
            bf16x8 kf1 = *(const bf16x8*)&Ksm[row][32 + quad * 8];
            s[nt] = __builtin_amdgcn_mfma_f32_16x16x32_bf16(kf0, qf0, s[nt], 0, 0, 0);
            s[nt] = __builtin_amdgcn_mfma_f32_16x16x32_bf16(kf1, qf1, s[nt], 0, 0, 0);
        }
        __builtin_amdgcn_s_setprio(0);

        if (diag) {
            #pragma unroll
            for (int nt = 0; nt < 4; nt++) {
                int koff = (nt & 1) * 32 + ((nt >> 1) << 2) + quad * 8;
                #pragma unroll
                for (int r = 0; r < 4; r++)
                    if (koff + r > wq * 16 + l15) s[nt][r] = -3.0e38f;
            }
        }

        // balanced max tree (v_max3-friendly)
        float m0 = fmaxf(fmaxf(s[0][0], s[0][1]), fmaxf(s[0][2], s[0][3]));
        float m1 = fmaxf(fmaxf(s[1][0], s[1][1]), fmaxf(s[1][2], s[1][3]));
        float m2 = fmaxf(fmaxf(s[2][0], s[2][1]), fmaxf(s[2][2], s[2][3]));
        float m3 = fmaxf(fmaxf(s[3][0], s[3][1]), fmaxf(s[3][2], s[3][3]));
        float mx = fmaxf(fmaxf(m0, m1), fmaxf(m2, m3));
        mx = fmaxf(mx, __shfl_xor(mx, 16));
        mx = fmaxf(mx, __shfl_xor(mx, 32));

        // T13 defer-max
        if (__any((mx - mrun) > 8.0f)) {
            float mnew  = fmaxf(mrun, mx);
            float alpha = exp2fast(mrun - mnew);
            mrun = mnew;
            #pragma unroll
            for (int nt = 0; nt < 4; nt++)
                #pragma unroll
                for (int r = 0; r < 4; r++) acc_o[nt][r] *= alpha;
            acc_l[0] *= alpha;
        }

        float pv[4][4];
        #pragma unroll
        for (int nt = 0; nt < 4; nt++)
            #pragma unroll
            for (int r = 0; r < 4; r++) pv[nt][r] = exp2fast(s[nt][r] - mrun);

        bf16x8 pf0, pf1;
        #pragma unroll
        for (int j = 0; j < 4; j++) {
            pf0[j]     = (__bf16)pv[0][j];
            pf0[4 + j] = (__bf16)pv[2][j];
            pf1[j]     = (__bf16)pv[1][j];
            pf1[4 + j] = (__bf16)pv[3][j];
        }

        __builtin_amdgcn_s_setprio(1);
        acc_l = __builtin_amdgcn_mfma_f32_16x16x32_bf16(af_l, pf0, acc_l, 0, 0, 0);
        acc_l = __builtin_amdgcn_mfma_f32_16x16x32_bf16(af_l, pf1, acc_l, 0, 0, 0);

        #pragma unroll
        for (int nt = 0; nt < 4; nt++) {
            bf16x8 vf0 = *(const bf16x8*)&Vsm[nt * 16 + l15][quad * 8];
            bf16x8 vf1 = *(const bf16x8*)&Vsm[nt * 16 + l15][32 + quad * 8];
            acc_o[nt] = __builtin_amdgcn_mfma_f32_16x16x32_bf16(vf0, pf0, acc_o[nt], 0, 0, 0);
            acc_o[nt] = __builtin_amdgcn_mfma_f32_16x16x32_bf16(vf1, pf1, acc_o[nt], 0, 0, 0);
        }
        __builtin_amdgcn_s_setprio(0);
    }

    float lall = __shfl(acc_l[0], l15);
    float inv  = 1.f / lall;
    size_t trow = (size_t)(b * TB) + qrow + l15;
    #pragma unroll
    for (int nt = 0; nt < 4; nt++) {
        bf16x4 st;
        #pragma unroll
        for (int r = 0; r < 4; r++) st[r] = (__bf16)(acc_o[nt][r] * inv);
        *(bf16x4*)&O[trow * CC + h * HD + nt * 16 + quad * 4] = st;
    }
}

extern "C" void kernel_launch(void* const* d_in, const int* in_sizes, int n_in,
                              void* d_out, int out_size, void* d_ws, size_t ws_size,
                              hipStream_t stream) {
    (void)in_sizes; (void)n_in; (void)out_size; (void)ws_size;
    const float* hidden   = (const float*)d_in[0];
    const float* W_attn   = (const float*)d_in[1];
    const float* b_attn   = (const float*)d_in[2];
    const float* W_proj   = (const float*)d_in[3];
    const float* b_proj   = (const float*)d_in[4];
    const float* kv_scale = (const float*)d_in[5];
    const float* kv_zp    = (const float*)d_in[6];
    float* out = (float*)d_out;

    __bf16* hb  = (__bf16*)d_ws;
    __bf16* wat = hb  + (size_t)4096 * 1024;
    __bf16* wpt = wat + (size_t)3072 * 1024;
    __bf16* qws = wpt + (size_t)1024 * 1024;
    __bf16* kws = qws + (size_t)2 * NH * TB * HD;
    __bf16* vws = kws + (size_t)2 * NH * TB * HD;
    __bf16* ows = vws + (size_t)2 * NH * TB * HD;

    prep_kernel<<<5120, 256, 0, stream>>>(hidden, hb, W_attn, wat, W_proj, wpt);

    gemm_bt<128, 0><<<dim3(24, 32), 256, 0, stream>>>(
        hb, wat, b_attn, qws, kws, vws, nullptr, 4096, 3072, 1024, kv_scale, kv_zp);

    attn_mfma<<<dim3(16 * 32), 512, 0, stream>>>(qws, kws, vws, ows);

    gemm_bt<64, 1><<<dim3(16, 32), 256, 0, stream>>>(
        ows, wpt, b_proj, nullptr, nullptr, nullptr, out, 4096, 1024, 1024,
        kv_scale, kv_zp);
}